// Round 2
// baseline (1031.175 us; speedup 1.0000x reference)
//
#include <hip/hip_runtime.h>
#include <math.h>

#define NTOK 131072
#define EMB  2048
#define UDIM 128
#define KDIM 2176   // EMB + UDIM
#define NE   64
#define TOPK 8

#define BM   128    // tokens per block
#define BK   64     // K chunk
#define BKP  68     // padded f32 row stride for staging
#define TM   8      // tokens per thread
#define TN   4      // experts per thread
#define LSTRD 65    // f64 logits row stride (doubles)

__global__ __launch_bounds__(256)
void gate_fused(const float* __restrict__ h,
                const float* __restrict__ u,
                const float* __restrict__ W,
                const float* __restrict__ b,
                float* __restrict__ out)
{
    // One shared buffer: f32 staging tiles during GEMM, f64 logits after.
    __shared__ double lsd[BM * LSTRD];                    // 66560 B
    float* xs = reinterpret_cast<float*>(lsd);            // 128*68 f32 = 34816 B
    float* ws = xs + BM * BKP;                            // 64*68 f32 = 17408 B (total 52224 B)

    const int tid = threadIdx.x;
    const int tx  = tid & 15;        // expert-dim coord
    const int ty  = tid >> 4;        // token-dim coord
    const int bm  = blockIdx.x * BM;

    double acc[TM][TN];
    #pragma unroll
    for (int i = 0; i < TM; ++i)
        #pragma unroll
        for (int j = 0; j < TN; ++j) acc[i][j] = 0.0;

    for (int k0 = 0; k0 < KDIM; k0 += BK) {
        const bool  fh   = (k0 < EMB);
        const float* src = fh ? h : u;
        const int   ld   = fh ? EMB : UDIM;
        const int   kb   = fh ? k0 : (k0 - EMB);

        // stage X tile: 128 tokens x 64 f32, coalesced float4
        #pragma unroll
        for (int r = 0; r < 8; ++r) {
            const int m = ty + r * 16;
            const float4 v = *reinterpret_cast<const float4*>(
                src + (size_t)(bm + m) * ld + kb + tx * 4);
            *reinterpret_cast<float4*>(&xs[m * BKP + tx * 4]) = v;
        }
        // stage W tile: 64 experts x 64 f32
        #pragma unroll
        for (int r = 0; r < 4; ++r) {
            const int e = ty + r * 16;
            const float4 v = *reinterpret_cast<const float4*>(
                W + (size_t)e * KDIM + k0 + tx * 4);
            *reinterpret_cast<float4*>(&ws[e * BKP + tx * 4]) = v;
        }
        __syncthreads();

        #pragma unroll 2
        for (int kk = 0; kk < BK; kk += 4) {
            double wd[TN][4];
            #pragma unroll
            for (int j = 0; j < TN; ++j) {
                const float4 wv = *reinterpret_cast<const float4*>(&ws[(tx + 16 * j) * BKP + kk]);
                wd[j][0] = (double)wv.x; wd[j][1] = (double)wv.y;
                wd[j][2] = (double)wv.z; wd[j][3] = (double)wv.w;
            }
            #pragma unroll
            for (int i = 0; i < TM; ++i) {
                const float4 xv = *reinterpret_cast<const float4*>(&xs[(ty + 16 * i) * BKP + kk]);
                const double x0 = (double)xv.x, x1 = (double)xv.y;
                const double x2 = (double)xv.z, x3 = (double)xv.w;
                #pragma unroll
                for (int j = 0; j < TN; ++j) {
                    acc[i][j] = fma(x0, wd[j][0], acc[i][j]);
                    acc[i][j] = fma(x1, wd[j][1], acc[i][j]);
                    acc[i][j] = fma(x2, wd[j][2], acc[i][j]);
                    acc[i][j] = fma(x3, wd[j][3], acc[i][j]);
                }
            }
        }
        __syncthreads();
    }

    // ---- logits (f64) + bias into LDS ----
    #pragma unroll
    for (int i = 0; i < TM; ++i) {
        const int m = ty + 16 * i;
        #pragma unroll
        for (int j = 0; j < TN; ++j) {
            const int e = tx + 16 * j;
            lsd[m * LSTRD + e] = acc[i][j] + (double)b[e];
        }
    }
    __syncthreads();

    // ---- per-token softmax + top-8 + renorm, all f64 (1 thread : 1 token) ----
    if (tid < BM) {
        double* row = lsd + tid * LSTRD;
        double mx = row[0];
        #pragma unroll
        for (int e = 1; e < NE; ++e) mx = fmax(mx, row[e]);
        double total = 0.0;
        #pragma unroll
        for (int e = 0; e < NE; ++e) {
            const double p = exp(row[e] - mx);
            row[e] = p;
            total += p;
        }
        double sum8 = 0.0;
        for (int s = 0; s < TOPK; ++s) {
            double best = -1.0; int bi = 0;
            for (int e = 0; e < NE; ++e) {
                const double p = row[e];
                if (p > best) { best = p; bi = e; }   // ties -> lowest index, matches lax.top_k
            }
            sum8 += best;
            row[bi] = -best;                           // mark selected via sign
        }
        // w_final = p / (sum_top8_p + 1e-9 * total)  [exact algebra of the reference]
        const double inv = 1.0 / (sum8 + 1e-9 * total);
        #pragma unroll
        for (int e = 0; e < NE; ++e) {
            const double p = row[e];
            row[e] = (p < 0.0) ? (-p) * inv : 0.0;
        }
    }
    __syncthreads();

    // ---- coalesced float4 store ----
    #pragma unroll
    for (int r = 0; r < 8; ++r) {
        const int m = ty + r * 16;
        float4 v;
        v.x = (float)lsd[m * LSTRD + tx * 4 + 0];
        v.y = (float)lsd[m * LSTRD + tx * 4 + 1];
        v.z = (float)lsd[m * LSTRD + tx * 4 + 2];
        v.w = (float)lsd[m * LSTRD + tx * 4 + 3];
        *reinterpret_cast<float4*>(out + (size_t)(bm + m) * NE + tx * 4) = v;
    }
}

extern "C" void kernel_launch(void* const* d_in, const int* in_sizes, int n_in,
                              void* d_out, int out_size, void* d_ws, size_t ws_size,
                              hipStream_t stream) {
    const float* h = (const float*)d_in[0];
    const float* u = (const float*)d_in[1];
    const float* W = (const float*)d_in[2];
    const float* b = (const float*)d_in[3];
    float* out = (float*)d_out;
    (void)in_sizes; (void)n_in; (void)out_size; (void)d_ws; (void)ws_size;

    dim3 grid(NTOK / BM);   // 1024
    dim3 block(256);
    hipLaunchKernelGGL(gate_fused, grid, block, 0, stream, h, u, W, b, out);
}

// Round 3
// 873.638 us; speedup vs baseline: 1.1803x; 1.1803x over previous
//
#include <hip/hip_runtime.h>
#include <math.h>

#define NTOK 131072
#define EMB  2048
#define UDIM 128
#define KDIM 2176   // EMB + UDIM
#define NE   64
#define TOPK 8

#define BM   128    // tokens per block
#define BK   64     // K chunk
#define BKP  68     // padded f32 row stride for staging
#define TM   8      // tokens per thread
#define TN   4      // experts per thread
#define LSTRD 65    // f64 logits row stride (doubles)
#define MARGIN 1e-4 // rank-8/9 gap below which we recompute in f64

__global__ __launch_bounds__(256)
void gate_fused(const float* __restrict__ h,
                const float* __restrict__ u,
                const float* __restrict__ W,
                const float* __restrict__ b,
                float* __restrict__ out)
{
    // Shared buffer: f32 staging tiles during GEMM, f64 logits after.
    // Mixed-type reuse is always separated by __syncthreads().
    __shared__ double lsd[BM * LSTRD];                    // 66560 B
    __shared__ int flaglist[BM];
    __shared__ int nflag;
    float* xs = reinterpret_cast<float*>(lsd);            // 128*68 f32
    float* ws = xs + BM * BKP;                            // 64*68 f32

    const int tid = threadIdx.x;
    const int tx  = tid & 15;        // expert-dim coord
    const int ty  = tid >> 4;        // token-dim coord
    const int bm  = blockIdx.x * BM;

    if (tid == 0) nflag = 0;

    float  acc[TM][TN];
    double acc64[TM][TN];
    #pragma unroll
    for (int i = 0; i < TM; ++i)
        #pragma unroll
        for (int j = 0; j < TN; ++j) { acc[i][j] = 0.f; acc64[i][j] = 0.0; }

    for (int k0 = 0; k0 < KDIM; k0 += BK) {
        const bool  fh   = (k0 < EMB);
        const float* src = fh ? h : u;
        const int   ld   = fh ? EMB : UDIM;
        const int   kb   = fh ? k0 : (k0 - EMB);

        // stage X tile: 128 tokens x 64 f32, coalesced float4
        #pragma unroll
        for (int r = 0; r < 8; ++r) {
            const int m = ty + r * 16;
            const float4 v = *reinterpret_cast<const float4*>(
                src + (size_t)(bm + m) * ld + kb + tx * 4);
            *reinterpret_cast<float4*>(&xs[m * BKP + tx * 4]) = v;
        }
        // stage W tile: 64 experts x 64 f32
        #pragma unroll
        for (int r = 0; r < 4; ++r) {
            const int e = ty + r * 16;
            const float4 v = *reinterpret_cast<const float4*>(
                W + (size_t)e * KDIM + k0 + tx * 4);
            *reinterpret_cast<float4*>(&ws[e * BKP + tx * 4]) = v;
        }
        __syncthreads();

        #pragma unroll 4
        for (int kk = 0; kk < BK; kk += 4) {
            float4 wv[TN];
            #pragma unroll
            for (int j = 0; j < TN; ++j)
                wv[j] = *reinterpret_cast<const float4*>(&ws[(tx + 16 * j) * BKP + kk]);
            #pragma unroll
            for (int i = 0; i < TM; ++i) {
                const float4 xv = *reinterpret_cast<const float4*>(&xs[(ty + 16 * i) * BKP + kk]);
                #pragma unroll
                for (int j = 0; j < TN; ++j) {
                    acc[i][j] = fmaf(xv.x, wv[j].x, acc[i][j]);
                    acc[i][j] = fmaf(xv.y, wv[j].y, acc[i][j]);
                    acc[i][j] = fmaf(xv.z, wv[j].z, acc[i][j]);
                    acc[i][j] = fmaf(xv.w, wv[j].w, acc[i][j]);
                }
            }
        }
        // drain chunk accumulators into f64 (bounds rounding error ~1e-6)
        #pragma unroll
        for (int i = 0; i < TM; ++i)
            #pragma unroll
            for (int j = 0; j < TN; ++j) {
                acc64[i][j] += (double)acc[i][j];
                acc[i][j] = 0.f;
            }
        __syncthreads();
    }

    // ---- logits (f64) + bias into LDS ----
    #pragma unroll
    for (int i = 0; i < TM; ++i) {
        const int m = ty + 16 * i;
        #pragma unroll
        for (int j = 0; j < TN; ++j) {
            const int e = tx + 16 * j;
            lsd[m * LSTRD + e] = acc64[i][j] + (double)b[e];
        }
    }
    __syncthreads();

    // ---- per-token: top-8 on f64 logits + margin + softmax (1 thread : 1 token) ----
    if (tid < BM) {
        double* row = lsd + tid * LSTRD;

        // 9 selection passes on logits: top-8 set + l8/l9 gap; ties -> lowest index
        unsigned long long selm = 0ULL;
        double mx = 0.0, l8 = 0.0, l9 = 0.0;
        for (int s = 0; s < TOPK + 1; ++s) {
            double best = -1e300; int bi = 0;
            #pragma unroll
            for (int e = 0; e < NE; ++e) {
                const double v = row[e];
                if (!((selm >> e) & 1ULL) && v > best) { best = v; bi = e; }
            }
            if (s == 0) mx = best;
            if (s < TOPK) selm |= 1ULL << bi;
            if (s == TOPK - 1) l8 = best;
            if (s == TOPK)     l9 = best;
        }
        if (l8 - l9 < MARGIN) {
            const int slot = atomicAdd(&nflag, 1);
            flaglist[slot] = tid;
        }

        // softmax values (f32 exp is plenty for values; selection already fixed)
        double tot = 0.0, s8 = 0.0;
        #pragma unroll
        for (int e = 0; e < NE; ++e) {
            const double p = (double)__expf((float)(row[e] - mx));
            tot += p;
            if ((selm >> e) & 1ULL) s8 += p;
            row[e] = p;
        }
        const double inv = 1.0 / (s8 + 1e-9 * tot);
        #pragma unroll
        for (int e = 0; e < NE; ++e)
            row[e] = ((selm >> e) & 1ULL) ? row[e] * inv : 0.0;
    }
    __syncthreads();

    // ---- coalesced float4 store ----
    #pragma unroll
    for (int r = 0; r < 8; ++r) {
        const int m = ty + r * 16;
        float4 v;
        v.x = (float)lsd[m * LSTRD + tx * 4 + 0];
        v.y = (float)lsd[m * LSTRD + tx * 4 + 1];
        v.z = (float)lsd[m * LSTRD + tx * 4 + 2];
        v.w = (float)lsd[m * LSTRD + tx * 4 + 3];
        *reinterpret_cast<float4*>(out + (size_t)(bm + m) * NE + tx * 4) = v;
    }
    __syncthreads();

    // ---- exact f64 refinement for margin-flagged tokens (rare: ~0.25%) ----
    const int nf = nflag;
    for (int f = 0; f < nf; ++f) {
        const int t = flaglist[f];
        const int e    = tid & 63;      // expert
        const int part = tid >> 6;      // K partition: 4 x 544
        const int ka = part * 544, kb2 = ka + 544;
        double s = 0.0;
        #pragma unroll 4
        for (int k = ka; k < kb2; ++k) {
            const float xv = (k < EMB) ? h[(size_t)(bm + t) * EMB + k]
                                       : u[(size_t)(bm + t) * UDIM + (k - EMB)];
            s = fma((double)xv, (double)W[(size_t)e * KDIM + k], s);
        }
        double* dscr = lsd;             // free after main store (barrier above)
        dscr[part * 64 + e] = s;
        __syncthreads();
        if (tid < NE) {
            const double l = dscr[tid] + dscr[64 + tid] + dscr[128 + tid] +
                             dscr[192 + tid] + (double)b[tid];
            dscr[512 + tid] = l;
        }
        __syncthreads();
        if (tid == 0) {
            double* dl = dscr + 512;
            double mx = dl[0];
            #pragma unroll
            for (int e2 = 1; e2 < NE; ++e2) mx = fmax(mx, dl[e2]);
            double tot = 0.0;
            #pragma unroll
            for (int e2 = 0; e2 < NE; ++e2) {
                const double p = exp(dl[e2] - mx);
                dl[e2] = p;
                tot += p;
            }
            double s8 = 0.0;
            for (int ss = 0; ss < TOPK; ++ss) {
                double best = -1.0; int bi = 0;
                for (int e2 = 0; e2 < NE; ++e2) {
                    const double p = dl[e2];
                    if (p > best) { best = p; bi = e2; }
                }
                s8 += best;
                dl[bi] = -best;
            }
            const double inv = 1.0 / (s8 + 1e-9 * tot);
            for (int e2 = 0; e2 < NE; ++e2) {
                const double p = dl[e2];
                out[(size_t)(bm + t) * NE + e2] = (float)((p < 0.0) ? (-p) * inv : 0.0);
            }
        }
        __syncthreads();
    }
}

extern "C" void kernel_launch(void* const* d_in, const int* in_sizes, int n_in,
                              void* d_out, int out_size, void* d_ws, size_t ws_size,
                              hipStream_t stream) {
    const float* h = (const float*)d_in[0];
    const float* u = (const float*)d_in[1];
    const float* W = (const float*)d_in[2];
    const float* b = (const float*)d_in[3];
    float* out = (float*)d_out;
    (void)in_sizes; (void)n_in; (void)out_size; (void)d_ws; (void)ws_size;

    dim3 grid(NTOK / BM);   // 1024
    dim3 block(256);
    hipLaunchKernelGGL(gate_fused, grid, block, 0, stream, h, u, W, b, out);
}

// Round 4
// 574.438 us; speedup vs baseline: 1.7951x; 1.5209x over previous
//
#include <hip/hip_runtime.h>
#include <math.h>

#define NTOK 131072
#define EMB  2048
#define UDIM 128
#define KDIM 2176   // EMB + UDIM
#define NE   64
#define TOPK 8

#define BM     128   // tokens per block (4 waves x 32 tokens)
#define BK     64    // K chunk (2 MFMA K-steps)
#define NCHUNK 34    // KDIM / BK
#define LSTR   65    // f32 logits row stride in LDS
#define MARGIN 1e-4f // rank-8/9 gap below which we recompute in f64

typedef short bf16x8 __attribute__((ext_vector_type(8)));
typedef float f32x4  __attribute__((ext_vector_type(4)));

union FragU { uint4 u; bf16x8 v; };

__device__ __forceinline__ unsigned rnbf(unsigned u) {
    // round-to-nearest-even f32 -> bf16 (top 16 bits of result)
    return u + 0x7FFFu + ((u >> 16) & 1u);
}

// 8 f32 -> packed bf16 hi plane (uint4) + lo plane (uint4)
__device__ __forceinline__ void cvt8(const float4 a, const float4 b,
                                     uint4& hi, uint4& lo) {
    float x[8] = {a.x, a.y, a.z, a.w, b.x, b.y, b.z, b.w};
    unsigned hh[4], ll[4];
    #pragma unroll
    for (int p = 0; p < 4; ++p) {
        const unsigned u0 = __float_as_uint(x[2*p]);
        const unsigned u1 = __float_as_uint(x[2*p+1]);
        const unsigned r0 = rnbf(u0), r1 = rnbf(u1);
        hh[p] = (r0 >> 16) | (r1 & 0xFFFF0000u);
        const float h0 = __uint_as_float(r0 & 0xFFFF0000u);
        const float h1 = __uint_as_float(r1 & 0xFFFF0000u);
        const unsigned s0 = rnbf(__float_as_uint(x[2*p]   - h0));
        const unsigned s1 = rnbf(__float_as_uint(x[2*p+1] - h1));
        ll[p] = (s0 >> 16) | (s1 & 0xFFFF0000u);
    }
    hi = make_uint4(hh[0], hh[1], hh[2], hh[3]);
    lo = make_uint4(ll[0], ll[1], ll[2], ll[3]);
}

__global__ __launch_bounds__(256)
void gate_fused(const float* __restrict__ h,
                const float* __restrict__ u,
                const float* __restrict__ W,
                const float* __restrict__ b,
                float* __restrict__ out)
{
    // Aliased LDS: W bf16 staging planes (16 KB) during GEMM,
    // f32 logits [128][65] after, f64 scratch during refinement.
    // All type reuse is separated by __syncthreads().
    __shared__ __align__(16) float ls[BM * LSTR];   // 33280 B
    __shared__ int flaglist[BM];
    __shared__ int nflag;
    unsigned short* wsH = reinterpret_cast<unsigned short*>(ls); // [64][64] swizzled
    unsigned short* wsL = wsH + 4096;

    const int tid  = threadIdx.x;
    const int lane = tid & 63;
    const int wid  = tid >> 6;
    const int bm   = blockIdx.x * BM;
    const int lrow = lane & 15;   // fragment row/col
    const int lk   = lane >> 4;   // fragment k-quarter

    if (tid == 0) nflag = 0;

    f32x4 accm[2][4], accc[2][4];
    #pragma unroll
    for (int mi = 0; mi < 2; ++mi)
        #pragma unroll
        for (int ni = 0; ni < 4; ++ni) {
            accm[mi][ni] = (f32x4){0.f, 0.f, 0.f, 0.f};
            accc[mi][ni] = (f32x4){0.f, 0.f, 0.f, 0.f};
        }

    // ---- load helpers ----
    auto loadX = [&](int c, float4 xr[8]) {
        const bool  fh  = (c < 32);
        const float* src = fh ? h : u;
        const int   ld  = fh ? EMB : UDIM;
        const int   kb  = c * BK - (fh ? 0 : EMB);
        #pragma unroll
        for (int mi = 0; mi < 2; ++mi) {
            const size_t ro = (size_t)(bm + wid*32 + mi*16 + lrow) * ld + kb + lk*8;
            #pragma unroll
            for (int s = 0; s < 2; ++s) {
                xr[mi*4 + s*2 + 0] = *reinterpret_cast<const float4*>(src + ro + s*32);
                xr[mi*4 + s*2 + 1] = *reinterpret_cast<const float4*>(src + ro + s*32 + 4);
            }
        }
    };
    auto loadW = [&](int c, float4 wr[4]) {
        const int e = tid >> 2, q = tid & 3;
        const float* p = W + (size_t)e * KDIM + c * BK + q * 16;
        #pragma unroll
        for (int i = 0; i < 4; ++i)
            wr[i] = *reinterpret_cast<const float4*>(p + i * 4);
    };
    auto stageW = [&](const float4 wr[4]) {
        const int e = tid >> 2, q = tid & 3;
        uint4 h0, l0, h1, l1;
        cvt8(wr[0], wr[1], h0, l0);
        cvt8(wr[2], wr[3], h1, l1);
        const int sw = e & 7;
        const int i0 = e*64 + (((q*2    ) ^ sw) * 8);
        const int i1 = e*64 + (((q*2 + 1) ^ sw) * 8);
        *reinterpret_cast<uint4*>(&wsH[i0]) = h0;
        *reinterpret_cast<uint4*>(&wsH[i1]) = h1;
        *reinterpret_cast<uint4*>(&wsL[i0]) = l0;
        *reinterpret_cast<uint4*>(&wsL[i1]) = l1;
    };
    auto compute = [&](const float4 xr[8]) {
        #pragma unroll
        for (int s = 0; s < 2; ++s) {
            FragU bh[4], bl[4];
            #pragma unroll
            for (int ni = 0; ni < 4; ++ni) {
                const int e   = ni*16 + lrow;
                const int kb  = s*4 + lk;
                const int idx = e*64 + ((kb ^ (e & 7)) * 8);
                bh[ni].u = *reinterpret_cast<const uint4*>(&wsH[idx]);
                bl[ni].u = *reinterpret_cast<const uint4*>(&wsL[idx]);
            }
            #pragma unroll
            for (int mi = 0; mi < 2; ++mi) {
                FragU ah, al;
                cvt8(xr[mi*4 + s*2], xr[mi*4 + s*2 + 1], ah.u, al.u);
                #pragma unroll
                for (int ni = 0; ni < 4; ++ni) {
                    accm[mi][ni] = __builtin_amdgcn_mfma_f32_16x16x32_bf16(ah.v, bh[ni].v, accm[mi][ni], 0, 0, 0);
                    accc[mi][ni] = __builtin_amdgcn_mfma_f32_16x16x32_bf16(ah.v, bl[ni].v, accc[mi][ni], 0, 0, 0);
                    accc[mi][ni] = __builtin_amdgcn_mfma_f32_16x16x32_bf16(al.v, bh[ni].v, accc[mi][ni], 0, 0, 0);
                }
            }
        }
    };

    // ---- main K loop: X prefetched in regs, W staged via LDS ----
    float4 xcur[8], xnxt[8], wcur[4], wnxt[4];
    loadW(0, wcur);
    loadX(0, xcur);
    for (int c = 0; c < NCHUNK; ++c) {
        stageW(wcur);
        if (c + 1 < NCHUNK) { loadW(c + 1, wnxt); loadX(c + 1, xnxt); }
        __syncthreads();            // ws tile visible
        compute(xcur);
        __syncthreads();            // all waves done reading ws
        #pragma unroll
        for (int i = 0; i < 8; ++i) xcur[i] = xnxt[i];
        #pragma unroll
        for (int i = 0; i < 4; ++i) wcur[i] = wnxt[i];
    }

    // ---- C-write: logits (+bias, f64 combine) into f32 LDS ----
    double bd[4];
    #pragma unroll
    for (int ni = 0; ni < 4; ++ni) bd[ni] = (double)b[ni*16 + lrow];
    #pragma unroll
    for (int mi = 0; mi < 2; ++mi)
        #pragma unroll
        for (int ni = 0; ni < 4; ++ni)
            #pragma unroll
            for (int r = 0; r < 4; ++r) {
                const int tl = wid*32 + mi*16 + lk*4 + r;
                const int e  = ni*16 + lrow;
                ls[tl * LSTR + e] =
                    (float)((double)accm[mi][ni][r] + (double)accc[mi][ni][r] + bd[ni]);
            }
    __syncthreads();

    // ---- per-token top-8 + margin + softmax (1 thread : 1 token) ----
    if (tid < BM) {
        float* row = ls + tid * LSTR;
        unsigned long long selm = 0ULL;
        float mx = 0.f, l8 = 0.f, l9 = 0.f;
        for (int s = 0; s < TOPK + 1; ++s) {
            float best = -1e30f; int bi = 0;
            #pragma unroll
            for (int e = 0; e < NE; ++e) {
                const float v = row[e];
                if (!((selm >> e) & 1ULL) && v > best) { best = v; bi = e; }
            }
            if (s == 0) mx = best;
            if (s < TOPK) selm |= 1ULL << bi;
            if (s == TOPK - 1) l8 = best;
            if (s == TOPK)     l9 = best;
        }
        if (l8 - l9 < MARGIN) {
            const int slot = atomicAdd(&nflag, 1);
            flaglist[slot] = tid;
        }
        float tot = 0.f, s8 = 0.f;
        #pragma unroll
        for (int e = 0; e < NE; ++e) {
            const float p = __expf(row[e] - mx);
            tot += p;
            if ((selm >> e) & 1ULL) s8 += p;
            row[e] = p;
        }
        const float inv = 1.f / (s8 + 1e-9f * tot);
        #pragma unroll
        for (int e = 0; e < NE; ++e)
            row[e] = ((selm >> e) & 1ULL) ? row[e] * inv : 0.f;
    }
    __syncthreads();

    // ---- coalesced float4 store ----
    {
        const int tx = tid & 15, ty = tid >> 4;
        #pragma unroll
        for (int r = 0; r < 8; ++r) {
            const int m = ty + r * 16;
            float4 v;
            v.x = ls[m * LSTR + tx*4 + 0];
            v.y = ls[m * LSTR + tx*4 + 1];
            v.z = ls[m * LSTR + tx*4 + 2];
            v.w = ls[m * LSTR + tx*4 + 3];
            *reinterpret_cast<float4*>(out + (size_t)(bm + m) * NE + tx*4) = v;
        }
    }
    __syncthreads();

    // ---- exact f64 refinement for margin-flagged tokens (~0.25%) ----
    const int nf = nflag;
    double* dscr = reinterpret_cast<double*>(ls);
    for (int f = 0; f < nf; ++f) {
        const int t    = flaglist[f];
        const int e    = tid & 63;
        const int part = tid >> 6;          // 4 K-partitions x 544
        const int ka = part * 544, kb2 = ka + 544;
        double s = 0.0;
        #pragma unroll 4
        for (int k = ka; k < kb2; ++k) {
            const float xv = (k < EMB) ? h[(size_t)(bm + t) * EMB + k]
                                       : u[(size_t)(bm + t) * UDIM + (k - EMB)];
            s = fma((double)xv, (double)W[(size_t)e * KDIM + k], s);
        }
        dscr[part * 64 + e] = s;
        __syncthreads();
        if (tid < NE) {
            const double l = dscr[tid] + dscr[64 + tid] + dscr[128 + tid] +
                             dscr[192 + tid] + (double)b[tid];
            dscr[512 + tid] = l;
        }
        __syncthreads();
        if (tid == 0) {
            double* dl = dscr + 512;
            double mx = dl[0];
            #pragma unroll
            for (int e2 = 1; e2 < NE; ++e2) mx = fmax(mx, dl[e2]);
            double tot = 0.0;
            #pragma unroll
            for (int e2 = 0; e2 < NE; ++e2) {
                const double p = exp(dl[e2] - mx);
                dl[e2] = p;
                tot += p;
            }
            double s8 = 0.0;
            for (int ss = 0; ss < TOPK; ++ss) {
                double best = -1.0; int bi = 0;
                for (int e2 = 0; e2 < NE; ++e2) {
                    const double p = dl[e2];
                    if (p > best) { best = p; bi = e2; }
                }
                s8 += best;
                dl[bi] = -best;
            }
            const double inv = 1.0 / (s8 + 1e-9 * tot);
            for (int e2 = 0; e2 < NE; ++e2) {
                const double p = dl[e2];
                out[(size_t)(bm + t) * NE + e2] = (float)((p < 0.0) ? (-p) * inv : 0.0);
            }
        }
        __syncthreads();
    }
}

extern "C" void kernel_launch(void* const* d_in, const int* in_sizes, int n_in,
                              void* d_out, int out_size, void* d_ws, size_t ws_size,
                              hipStream_t stream) {
    const float* h = (const float*)d_in[0];
    const float* u = (const float*)d_in[1];
    const float* W = (const float*)d_in[2];
    const float* b = (const float*)d_in[3];
    float* out = (float*)d_out;
    (void)in_sizes; (void)n_in; (void)out_size; (void)d_ws; (void)ws_size;

    dim3 grid(NTOK / BM);   // 1024
    dim3 block(256);
    hipLaunchKernelGGL(gate_fused, grid, block, 0, stream, h, u, W, b, out);
}

// Round 6
// 438.462 us; speedup vs baseline: 2.3518x; 1.3101x over previous
//
#include <hip/hip_runtime.h>
#include <math.h>

#define NTOK 131072
#define EMB  2048
#define UDIM 128
#define KDIM 2176   // EMB + UDIM
#define NE   64
#define TOPK 8

#define BM     128   // tokens per block (4 waves x 32 tokens)
#define BK     64    // K chunk (2 MFMA K-steps)
#define NCHUNK 34    // KDIM / BK
#define NKSTEP 68    // KDIM / 32
#define LSTR   65    // f32 logits row stride in LDS
#define MARGIN 1e-4f // rank-8/9 gap below which we recompute in f64
#define WPLANE ((size_t)NKSTEP * 64 * 32)   // bf16 elems per W plane

typedef short bf16x8 __attribute__((ext_vector_type(8)));
typedef float f32x4  __attribute__((ext_vector_type(4)));

union FragU { uint4 u; bf16x8 v; };

__device__ __forceinline__ unsigned rnbf(unsigned u) {
    // round-to-nearest-even f32 -> bf16 (result in top 16 bits)
    return u + 0x7FFFu + ((u >> 16) & 1u);
}

// 8 f32 -> packed bf16 hi plane + lo plane (proven RNE split, round 3)
__device__ __forceinline__ void cvt8(const float4 a, const float4 b,
                                     uint4& hi, uint4& lo) {
    const float x[8] = {a.x, a.y, a.z, a.w, b.x, b.y, b.z, b.w};
    unsigned hh[4], ll[4];
    #pragma unroll
    for (int p = 0; p < 4; ++p) {
        const unsigned u0 = __float_as_uint(x[2*p]);
        const unsigned u1 = __float_as_uint(x[2*p+1]);
        const unsigned r0 = rnbf(u0), r1 = rnbf(u1);
        hh[p] = (r0 >> 16) | (r1 & 0xFFFF0000u);
        const float h0 = __uint_as_float(r0 & 0xFFFF0000u);
        const float h1 = __uint_as_float(r1 & 0xFFFF0000u);
        const unsigned s0 = rnbf(__float_as_uint(x[2*p]   - h0));
        const unsigned s1 = rnbf(__float_as_uint(x[2*p+1] - h1));
        ll[p] = (s0 >> 16) | (s1 & 0xFFFF0000u);
    }
    hi = make_uint4(hh[0], hh[1], hh[2], hh[3]);
    lo = make_uint4(ll[0], ll[1], ll[2], ll[3]);
}

// W f32 -> bf16 hi/lo planes in per-lane fragment order:
// wh[(ks*64 + e)*32 + lk*8 + j] = bf16(W[e][ks*32 + lk*8 + j])
__global__ __launch_bounds__(256)
void prep_w(const float* __restrict__ W,
            unsigned short* __restrict__ wh,
            unsigned short* __restrict__ wl)
{
    const int t = blockIdx.x * 256 + threadIdx.x;   // [0, 68*64*4)
    if (t >= NKSTEP * 64 * 4) return;
    const int lk = t & 3, e = (t >> 2) & 63, ks = t >> 8;
    const float* p = W + (size_t)e * KDIM + ks * 32 + lk * 8;
    const float4 a = *reinterpret_cast<const float4*>(p);
    const float4 c = *reinterpret_cast<const float4*>(p + 4);
    uint4 hi, lo;
    cvt8(a, c, hi, lo);
    const size_t di = ((size_t)ks * 64 + e) * 32 + lk * 8;
    *reinterpret_cast<uint4*>(wh + di) = hi;
    *reinterpret_cast<uint4*>(wl + di) = lo;
}

__global__ void zero_flags(int* flagbuf) {
    if (threadIdx.x == 0 && blockIdx.x == 0) flagbuf[0] = 0;
}

__global__ __launch_bounds__(256)
void gate_main(const float* __restrict__ h,
               const float* __restrict__ u,
               const unsigned short* __restrict__ wh,
               const unsigned short* __restrict__ wl,
               const float* __restrict__ b,
               int* __restrict__ flagbuf,
               float* __restrict__ out)
{
    __shared__ __align__(16) float ls[BM * LSTR];   // 33280 B
    __shared__ int flaglist[BM];
    __shared__ int nflag;

    const int tid  = threadIdx.x;
    const int lane = tid & 63;
    const int wid  = tid >> 6;
    const int bm   = blockIdx.x * BM;
    const int lrow = lane & 15;   // fragment row/col
    const int lk   = lane >> 4;   // fragment k-quarter

    if (tid == 0) nflag = 0;

    f32x4 acc[2][4];
    #pragma unroll
    for (int mi = 0; mi < 2; ++mi)
        #pragma unroll
        for (int ni = 0; ni < 4; ++ni)
            acc[mi][ni] = (f32x4){0.f, 0.f, 0.f, 0.f};

    auto loadX = [&](int c, float4 xr[8]) {
        const bool  fh  = (c < 32);
        const float* src = fh ? h : u;
        const int   ld  = fh ? EMB : UDIM;
        const int   kb  = c * BK - (fh ? 0 : EMB);
        #pragma unroll
        for (int mi = 0; mi < 2; ++mi) {
            const size_t ro = (size_t)(bm + wid*32 + mi*16 + lrow) * ld + kb + lk*8;
            #pragma unroll
            for (int s = 0; s < 2; ++s) {
                xr[mi*4 + s*2 + 0] = *reinterpret_cast<const float4*>(src + ro + s*32);
                xr[mi*4 + s*2 + 1] = *reinterpret_cast<const float4*>(src + ro + s*32 + 4);
            }
        }
    };

    auto compute = [&](const float4 xr[8], int c) {
        #pragma unroll
        for (int s = 0; s < 2; ++s) {
            const int ks = c*2 + s;
            const uint4* bH = reinterpret_cast<const uint4*>(wh + (size_t)ks * 2048);
            const uint4* bL = reinterpret_cast<const uint4*>(wl + (size_t)ks * 2048);
            FragU bh[4], bl[4];
            #pragma unroll
            for (int ni = 0; ni < 4; ++ni) {
                const int off = (ni*16 + lrow)*4 + lk;
                bh[ni].u = bH[off];
                bl[ni].u = bL[off];
            }
            #pragma unroll
            for (int mi = 0; mi < 2; ++mi) {
                FragU ah, al;
                cvt8(xr[mi*4 + s*2], xr[mi*4 + s*2 + 1], ah.u, al.u);
                #pragma unroll
                for (int ni = 0; ni < 4; ++ni) {
                    acc[mi][ni] = __builtin_amdgcn_mfma_f32_16x16x32_bf16(ah.v, bh[ni].v, acc[mi][ni], 0, 0, 0);
                    acc[mi][ni] = __builtin_amdgcn_mfma_f32_16x16x32_bf16(ah.v, bl[ni].v, acc[mi][ni], 0, 0, 0);
                    acc[mi][ni] = __builtin_amdgcn_mfma_f32_16x16x32_bf16(al.v, bh[ni].v, acc[mi][ni], 0, 0, 0);
                }
            }
        }
    };

    // ---- barrier-free main K loop: X prefetched 1 chunk ahead ----
    float4 xcur[8], xnxt[8];
    loadX(0, xcur);
    for (int c = 0; c < NCHUNK; ++c) {
        if (c + 1 < NCHUNK) loadX(c + 1, xnxt);
        compute(xcur, c);
        #pragma unroll
        for (int i = 0; i < 8; ++i) xcur[i] = xnxt[i];
    }

    // ---- C-write: logits + bias into f32 LDS ----
    #pragma unroll
    for (int mi = 0; mi < 2; ++mi)
        #pragma unroll
        for (int ni = 0; ni < 4; ++ni) {
            const float be = b[ni*16 + lrow];
            #pragma unroll
            for (int r = 0; r < 4; ++r) {
                const int tl = wid*32 + mi*16 + lk*4 + r;
                const int e  = ni*16 + lrow;
                ls[tl * LSTR + e] = acc[mi][ni][r] + be;
            }
        }
    __syncthreads();

    // ---- per-token top-8 + margin + softmax (1 thread : 1 token) ----
    if (tid < BM) {
        float* row = ls + tid * LSTR;
        unsigned long long selm = 0ULL;
        float mx = 0.f, l8 = 0.f, l9 = 0.f;
        for (int s = 0; s < TOPK + 1; ++s) {
            float best = -1e30f; int bi = 0;
            #pragma unroll
            for (int e = 0; e < NE; ++e) {
                const float v = row[e];
                if (!((selm >> e) & 1ULL) && v > best) { best = v; bi = e; }
            }
            if (s == 0) mx = best;
            if (s < TOPK) selm |= 1ULL << bi;
            if (s == TOPK - 1) l8 = best;
            if (s == TOPK)     l9 = best;
        }
        if (l8 - l9 < MARGIN) {
            const int slot = atomicAdd(&nflag, 1);
            flaglist[slot] = tid;
        }
        float tot = 0.f, s8 = 0.f;
        #pragma unroll
        for (int e = 0; e < NE; ++e) {
            const float p = __expf(row[e] - mx);
            tot += p;
            if ((selm >> e) & 1ULL) s8 += p;
            row[e] = p;
        }
        const float inv = 1.f / (s8 + 1e-9f * tot);
        #pragma unroll
        for (int e = 0; e < NE; ++e)
            row[e] = ((selm >> e) & 1ULL) ? row[e] * inv : 0.f;
    }
    __syncthreads();

    // ---- coalesced float4 store ----
    {
        const int tx = tid & 15, ty = tid >> 4;
        #pragma unroll
        for (int r = 0; r < 8; ++r) {
            const int m = ty + r * 16;
            float4 v;
            v.x = ls[m * LSTR + tx*4 + 0];
            v.y = ls[m * LSTR + tx*4 + 1];
            v.z = ls[m * LSTR + tx*4 + 2];
            v.w = ls[m * LSTR + tx*4 + 3];
            *reinterpret_cast<float4*>(out + (size_t)(bm + m) * NE + tx*4) = v;
        }
    }

    // ---- publish flagged tokens for the refine kernel (device-scope atomics) ----
    if (tid < nflag) {
        const int slot = atomicAdd(flagbuf, 1);
        flagbuf[1 + slot] = bm + flaglist[tid];
    }
}

// ---- exact f64 referee for margin-flagged tokens (reads original f32 W) ----
__global__ __launch_bounds__(256)
void gate_refine(const float* __restrict__ h,
                 const float* __restrict__ u,
                 const float* __restrict__ W,
                 const float* __restrict__ b,
                 const int* __restrict__ flagbuf,   // [0]=count, then token ids
                 float* __restrict__ out)
{
    __shared__ double dscr[576];
    const int nf = flagbuf[0];
    for (int f = blockIdx.x; f < nf; f += gridDim.x) {
        const int tok  = flagbuf[1 + f];
        const int tid  = threadIdx.x;
        const int e    = tid & 63;
        const int part = tid >> 6;          // 4 K-partitions x 544
        const int ka = part * 544, kb2 = ka + 544;
        double s = 0.0;
        #pragma unroll 4
        for (int k = ka; k < kb2; ++k) {
            const float xv = (k < EMB) ? h[(size_t)tok * EMB + k]
                                       : u[(size_t)tok * UDIM + (k - EMB)];
            s = fma((double)xv, (double)W[(size_t)e * KDIM + k], s);
        }
        dscr[part * 64 + e] = s;
        __syncthreads();
        if (tid < NE) {
            const double l = dscr[tid] + dscr[64 + tid] + dscr[128 + tid] +
                             dscr[192 + tid] + (double)b[tid];
            dscr[512 + tid] = l;
        }
        __syncthreads();
        if (tid == 0) {
            double* dl = dscr + 512;
            double mx = dl[0];
            #pragma unroll
            for (int e2 = 1; e2 < NE; ++e2) mx = fmax(mx, dl[e2]);
            double tot = 0.0;
            #pragma unroll
            for (int e2 = 0; e2 < NE; ++e2) {
                const double p = exp(dl[e2] - mx);
                dl[e2] = p;
                tot += p;
            }
            double s8 = 0.0;
            for (int ss = 0; ss < TOPK; ++ss) {
                double best = -1.0; int bi = 0;
                for (int e2 = 0; e2 < NE; ++e2) {
                    const double p = dl[e2];
                    if (p > best) { best = p; bi = e2; }
                }
                s8 += best;
                dl[bi] = -best;
            }
            const double inv = 1.0 / (s8 + 1e-9 * tot);
            for (int e2 = 0; e2 < NE; ++e2) {
                const double p = dl[e2];
                out[(size_t)tok * NE + e2] = (float)((p < 0.0) ? (-p) * inv : 0.0);
            }
        }
        __syncthreads();
    }
}

extern "C" void kernel_launch(void* const* d_in, const int* in_sizes, int n_in,
                              void* d_out, int out_size, void* d_ws, size_t ws_size,
                              hipStream_t stream) {
    const float* h = (const float*)d_in[0];
    const float* u = (const float*)d_in[1];
    const float* W = (const float*)d_in[2];
    const float* b = (const float*)d_in[3];
    float* out = (float*)d_out;
    (void)in_sizes; (void)n_in; (void)out_size; (void)ws_size;

    unsigned short* wh = (unsigned short*)d_ws;
    unsigned short* wl = wh + WPLANE;
    int* flagbuf = (int*)(wl + WPLANE);   // [0]=count, then up to NTOK ids

    hipLaunchKernelGGL(zero_flags, dim3(1), dim3(64), 0, stream, flagbuf);
    hipLaunchKernelGGL(prep_w, dim3(NKSTEP), dim3(256), 0, stream, W, wh, wl);
    hipLaunchKernelGGL(gate_main, dim3(NTOK / BM), dim3(256), 0, stream,
                       h, u, wh, wl, b, flagbuf, out);
    hipLaunchKernelGGL(gate_refine, dim3(256), dim3(256), 0, stream,
                       h, u, W, b, flagbuf, out);
}